// Round 5
// baseline (1865.853 us; speedup 1.0000x reference)
//
#include <hip/hip_runtime.h>
#include <cstdint>
#include <cstddef>

#define BATCH 8
#define SEQ   4096
#define DS    512
#define JPL   8              // states per lane (64 lanes * 8 = 512)
#define BLK   8              // time steps per LDS block
#define NBLK  (SEQ / BLK)    // 512
#define LN_EPS 1e-5f

typedef float v2f __attribute__((ext_vector_type(2)));
typedef float v4f __attribute__((ext_vector_type(4)));

static __device__ __forceinline__ v2f lo2(v4f x) { return __builtin_shufflevector(x, x, 0, 1); }
static __device__ __forceinline__ v2f hi2(v4f x) { return __builtin_shufflevector(x, x, 2, 3); }

#define LGKM0() asm volatile("s_waitcnt lgkmcnt(0)" ::: "memory")

// ---- DPP wave64 reduction: row_shr 1/2/4/8, row_bcast15/31 -> lane 63 ----
template <int CTRL>
__device__ __forceinline__ float dpp_add(float v) {
  int t = __builtin_amdgcn_update_dpp(0, __builtin_bit_cast(int, v), CTRL, 0xF, 0xF, true);
  return v + __builtin_bit_cast(float, t);
}
__device__ __forceinline__ float wave_sum64(float v) {
  v = dpp_add<0x111>(v);
  v = dpp_add<0x112>(v);
  v = dpp_add<0x114>(v);
  v = dpp_add<0x118>(v);
  v = dpp_add<0x142>(v);
  v = dpp_add<0x143>(v);
  return v;  // valid in lane 63
}
__device__ __forceinline__ float bcast63(float v) {
  return __builtin_bit_cast(float, __builtin_amdgcn_readlane(__builtin_bit_cast(int, v), 63));
}

// async HBM -> LDS: per-lane 16B from g, LDS dest = uniform base + lane*16
__device__ __forceinline__ void ld16(const float* g, float* l) {
  __builtin_amdgcn_global_load_lds(
      (const __attribute__((address_space(1))) void*)g,
      (__attribute__((address_space(3))) void*)l, 16, 0, 0);
}

// intra-lane trees over v2f[4]
__device__ __forceinline__ float t4s(const v2f* a) {
  v2f s = (a[0] + a[1]) + (a[2] + a[3]);
  return s.x + s.y;
}
__device__ __forceinline__ float t4m(const v2f* a, const v2f* b) {
  v2f s = a[0] * b[0];
  s = __builtin_elementwise_fma(a[1], b[1], s);
  v2f r = a[2] * b[2];
  r = __builtin_elementwise_fma(a[3], b[3], r);
  v2f q = s + r;
  return q.x + q.y;
}

// ---------------- linearized-pipeline scan: 3 waves per batch ---------------
// hr_{t+1} = al*(Q(x)hr_t) + be*Q + R ;  Q = a*w*rs, R = a*bias*rs + b*x_{t+1}
// wave 0 (consumer): u-reductions have 1-step slack -> DPP off the serial cycle
// wave 1: DMA x, out-writes (y finalized from m-partials + AB + RHO), reduce
//         wave-2 partials into RHO scalars (one interval ahead of use)
// wave 2: rs tile + 7 vol/x-only partial sums, two blocks ahead (global x/vol
//         prefetched one interval early)
__global__ __launch_bounds__(192, 1) void ssm_scan(
    const float* __restrict__ x, const float* __restrict__ vol,
    const float* __restrict__ llr, const float* __restrict__ logb,
    const float* __restrict__ cvec, const float* __restrict__ lstp,
    const float* __restrict__ vgat, const float* __restrict__ lnw,
    const float* __restrict__ lnb, const float* __restrict__ alph,
    const float* __restrict__ logd, float* __restrict__ out)
{
  __shared__ __attribute__((aligned(16))) float Xt[3][4096];   // x tiles (48KB)
  __shared__ __attribute__((aligned(16))) float RS[3][4096];   // rs tiles (48KB)
  __shared__ __attribute__((aligned(16))) float PART[2][4096]; // helper partials (32KB)
  __shared__ __attribute__((aligned(16))) float RHO[32][8];    // reduced helper sums
  __shared__ __attribute__((aligned(16))) float AB2[32][2];    // per-step (al,be)
  __shared__ __attribute__((aligned(16))) float SC[2][512];    // per-lane m-partials

  const int b    = blockIdx.x;
  const int lane = threadIdx.x & 63;
  const int wid  = threadIdx.x >> 6;

  if (wid == 1) {
    // ======== DMA + out-write + partial-reduce wave ========
    const float* xg = x + (size_t)b * SEQ * DS + lane * JPL;
    float* ob = out + (size_t)b * SEQ * DS;
    float al_  = 1.0f / (1.0f + expf(-alph[0]));
    float dd   = expf(logd[0]);
    float coef = __builtin_fmaf(1.0f - al_, dd, al_);
    float c1   = 1.0f - al_;

    auto dma_blk = [&](int blk, float* Xs) {
#pragma unroll
      for (int u = 0; u < BLK; ++u) {
        const float* row = xg + (size_t)(blk * BLK + u) * DS;
        ld16(row,     Xs + u * 512);
        ld16(row + 4, Xs + u * 512 + 256);
      }
    };
    auto out_blk = [&](int blk) {
      const float* Xs  = Xt[blk % 3];
      const float* SCs = SC[blk & 1];
#pragma unroll
      for (int u = 0; u < BLK; ++u) {
        int s = blk * BLK + u;
        float msum = bcast63(wave_sum64(SCs[u * 64 + lane]));
        float a_ = AB2[s & 31][0], b_ = AB2[s & 31][1];
        float y  = __builtin_fmaf(a_, msum,
                     __builtin_fmaf(b_, RHO[s & 31][5], RHO[s & 31][6]));
        float scv = c1 * y;
        v4f xa = *(const v4f*)(Xs + u * 512 + lane * 4);
        v4f xb = *(const v4f*)(Xs + u * 512 + 256 + lane * 4);
        float* row = ob + (size_t)s * DS + lane * 8;
        *(v4f*)(row)     = xa * coef + scv;
        *(v4f*)(row + 4) = xb * coef + scv;
      }
    };
    auto reduce_part = [&](int blk) {
      const float* P = PART[blk & 1];
#pragma unroll
      for (int u = 0; u < BLK; ++u) {
        v4f pA = *(const v4f*)(P + u * 512 + lane * 8);
        v4f pB = *(const v4f*)(P + u * 512 + lane * 8 + 4);
        float r0 = bcast63(wave_sum64(pA[0]));
        float r1 = bcast63(wave_sum64(pA[1]));
        float r2 = bcast63(wave_sum64(pA[2]));
        float r3 = bcast63(wave_sum64(pA[3]));
        float r4 = bcast63(wave_sum64(pB[0]));
        float r5 = bcast63(wave_sum64(pB[1]));
        float r6 = bcast63(wave_sum64(pB[2]));
        if (lane == 0) {
          int s = (blk * BLK + u) & 31;
          RHO[s][0] = r0; RHO[s][1] = r1; RHO[s][2] = r2; RHO[s][3] = r3;
          RHO[s][4] = r4; RHO[s][5] = r5; RHO[s][6] = r6;
        }
      }
    };

    // preA: stage block 0
    dma_blk(0, Xt[0]);
    __syncthreads();
    // preB: RHO for block 0; stage block 1
    reduce_part(0);
    LGKM0();
    __builtin_amdgcn_sched_barrier(0);
    dma_blk(1, Xt[1]);
    __syncthreads();
#pragma unroll 1
    for (int i = 0; i < NBLK; ++i) {
      if (i >= 1) out_blk(i - 1);                 // reads Xt[(i-1)%3]
      LGKM0();                                    // before dma rewrites (i+2)%3==(i-1)%3
      __builtin_amdgcn_sched_barrier(0);
      if (i + 2 < NBLK) dma_blk(i + 2, Xt[(i + 2) % 3]);
      if (i + 1 < NBLK) reduce_part(i + 1);
      __syncthreads();
    }
    out_blk(NBLK - 1);
  } else if (wid == 2) {
    // ======== helper wave: rs tiles + 7 vol/x-only partial sums ========
    v2f gate[4], awc[4], abc[4], cwc[4], cbc[4], bdv[4];
#pragma unroll
    for (int j = 0; j < JPL; ++j) {
      int n = lane * JPL + j;
      float lam = -expf(llr[n]);
      float st  = expf(lstp[n]);
      float z   = st * lam;
      float ad  = (2.0f + z) / (2.0f - z);
      float bdd = st * (1.0f + ad) * expf(logb[n]) * 0.5f;
      float wv  = lnw[n], bi = lnb[n], cv = cvec[n];
      gate[j >> 1][j & 1] = 1.0f / (1.0f + expf(-vgat[n]));
      awc[j >> 1][j & 1]  = ad * wv;
      abc[j >> 1][j & 1]  = ad * bi;
      cwc[j >> 1][j & 1]  = cv * wv;
      cbc[j >> 1][j & 1]  = cv * bi;
      bdv[j >> 1][j & 1]  = bdd;
    }
    const float* xq = x + (size_t)b * SEQ * DS + lane * JPL;
    const float* vg = vol + (size_t)b * SEQ;

    v4f XP[16];  // x_{t+1} rows for the block being processed
    v4f VPa, VPb;

    auto pf = [&](int blk) {   // load vol/x' for block blk into regs
      VPa = *(const v4f*)(vg + blk * BLK);
      VPb = *(const v4f*)(vg + blk * BLK + 4);
#pragma unroll
      for (int u = 0; u < BLK; ++u) {
        int r = blk * BLK + u + 1;
        if (r > SEQ - 1) r = SEQ - 1;            // last row: value unused
        XP[2 * u]     = *(const v4f*)(xq + (size_t)r * DS);
        XP[2 * u + 1] = *(const v4f*)(xq + (size_t)r * DS + 4);
      }
    };
    auto work = [&](int blk) {
      float* RSs = RS[blk % 3];
      float* Pp  = PART[blk & 1];
#pragma unroll
      for (int u = 0; u < BLK; ++u) {
        float vt = (u < 4) ? VPa[u] : VPb[u - 4];
        v2f rsv[4];
#pragma unroll
        for (int k = 0; k < 4; ++k) {
          v2f den = gate[k] * vt + 1.0f;
          rsv[k].x = __builtin_amdgcn_rcpf(den.x);
          rsv[k].y = __builtin_amdgcn_rcpf(den.y);
        }
        v4f r03 = {rsv[0].x, rsv[0].y, rsv[1].x, rsv[1].y};
        v4f r47 = {rsv[2].x, rsv[2].y, rsv[3].x, rsv[3].y};
        *(v4f*)(RSs + u * 512 + lane * 4)       = r03;
        *(v4f*)(RSs + u * 512 + 256 + lane * 4) = r47;
        v2f xr[4] = {lo2(XP[2 * u]), hi2(XP[2 * u]),
                     lo2(XP[2 * u + 1]), hi2(XP[2 * u + 1])};
        v2f Qv[4], Rv[4], cwv[4], cbv[4];
#pragma unroll
        for (int k = 0; k < 4; ++k) {
          Qv[k]  = awc[k] * rsv[k];
          Rv[k]  = __builtin_elementwise_fma(bdv[k], xr[k], abc[k] * rsv[k]);
          cwv[k] = cwc[k] * rsv[k];
          cbv[k] = cbc[k] * rsv[k];
        }
        float pQ  = t4s(Qv),  pQQ = t4m(Qv, Qv), pQR = t4m(Qv, Rv);
        float pR  = t4s(Rv),  pRR = t4m(Rv, Rv);
        float pcw = t4s(cwv), pcb = t4s(cbv);
        *(v4f*)(Pp + u * 512 + lane * 8)     = (v4f){pQ, pQQ, pQR, pR};
        *(v4f*)(Pp + u * 512 + lane * 8 + 4) = (v4f){pRR, pcw, pcb, 0.0f};
      }
    };

    // preA: block 0 (direct); preB: block 1 (direct) + prefetch block 2
    pf(0); work(0);
    __syncthreads();
    pf(1); work(1);
    if (2 < NBLK) pf(2);
    __syncthreads();
#pragma unroll 1
    for (int i = 0; i < NBLK; ++i) {
      if (i + 2 < NBLK) work(i + 2);
      if (i + 3 < NBLK) pf(i + 3);
      __syncthreads();
    }
  } else {
    // ======================== consumer wave ========================
    v2f aw[4], abc2[4], cwc2[4], bdv[4];
#pragma unroll
    for (int j = 0; j < JPL; ++j) {
      int n = lane * JPL + j;
      float lam = -expf(llr[n]);
      float st  = expf(lstp[n]);
      float z   = st * lam;
      float ad  = (2.0f + z) / (2.0f - z);
      float bdd = st * (1.0f + ad) * expf(logb[n]) * 0.5f;
      float wv  = lnw[n], bi = lnb[n], cv = cvec[n];
      aw[j >> 1][j & 1]   = ad * wv;
      abc2[j >> 1][j & 1] = ad * bi;
      cwc2[j >> 1][j & 1] = cv * wv;
      bdv[j >> 1][j & 1]  = bdd;
    }
    v2f hr[4];
    float al = 0.0f, be = 0.0f;
    float sU = 0.0f, sUU = 0.0f, sUQ = 0.0f, sUR = 0.0f;

    auto cstep = [&](int t, const float* RSs, const float* xrow, bool first0) {
      const int u = t & 7;
      const int s = (t - 1) & 31;
      v4f rs0 = *(const v4f*)(RSs + u * 512 + lane * 4);
      v4f rs1 = *(const v4f*)(RSs + u * 512 + 256 + lane * 4);
      v4f xa  = *(const v4f*)(xrow + lane * 4);
      v4f xb  = *(const v4f*)(xrow + 256 + lane * 4);
      float S1h, S2h;
      if (first0) {
        float s1 = t4s(hr);
        float s2 = t4m(hr, hr);
        S1h = bcast63(wave_sum64(s1));
        S2h = bcast63(wave_sum64(s2));
      } else {
        v4f rhoA = *(const v4f*)(&RHO[s][0]);      // (SQ, SQQ, SQR, SR)
        float rhoRR = RHO[s][4];
        float t0 = __builtin_fmaf(be, rhoA[0], rhoA[3]);
        S1h = __builtin_fmaf(al, sU, t0);
        float a2 = al * al, tw = al + al;
        float ab2 = tw * be, b2 = be * be, bb = be + be;
        float X3 = __builtin_fmaf(bb, rhoA[2], rhoRR);
        X3 = __builtin_fmaf(b2, rhoA[1], X3);
        X3 = __builtin_fmaf(tw, sUR, X3);
        X3 = __builtin_fmaf(ab2, sUQ, X3);
        S2h = __builtin_fmaf(a2, sUU, X3);
      }
      float mu  = S1h * (1.0f / DS);
      float m2e = __builtin_fmaf(S2h, 1.0f / DS, LN_EPS);
      float var = __builtin_fmaf(-mu, mu, m2e);
      float inv = __builtin_amdgcn_rsqf(var);
      al = inv;
      be = -inv * mu;
      if (lane == 0) { AB2[t & 31][0] = al; AB2[t & 31][1] = be; }
      // vectors (all off the scalar cycle except hr/u)
      v2f rsv[4] = {lo2(rs0), hi2(rs0), lo2(rs1), hi2(rs1)};
      v2f xs[4]  = {lo2(xa), hi2(xa), lo2(xb), hi2(xb)};
      v2f Qv[4], Rv[4], uv[4], mv[4];
#pragma unroll
      for (int k = 0; k < 4; ++k) {
        Qv[k] = aw[k] * rsv[k];
        Rv[k] = __builtin_elementwise_fma(bdv[k], xs[k], abc2[k] * rsv[k]);
        uv[k] = Qv[k] * hr[k];
        mv[k] = (cwc2[k] * rsv[k]) * hr[k];
      }
      float su  = t4s(uv);
      float suu = t4m(uv, uv);
      float suq = t4m(uv, Qv);
      float sur = t4m(uv, Rv);
      float sm  = t4s(mv);
      SC[(t >> 3) & 1][u * 64 + lane] = sm;
      v2f av = {al, al}, bv = {be, be};
#pragma unroll
      for (int k = 0; k < 4; ++k)
        hr[k] = __builtin_elementwise_fma(av, uv[k],
                  __builtin_elementwise_fma(bv, Qv[k], Rv[k]));
      // sigma_t for next step's scalars (DPP has a full step of slack)
      sU  = bcast63(wave_sum64(su));
      sUU = bcast63(wave_sum64(suu));
      sUQ = bcast63(wave_sum64(suq));
      sUR = bcast63(wave_sum64(sur));
    };

    __syncthreads();  // preA
    __syncthreads();  // preB
    // hr_0 = b_disc * x_0  (block 0 sealed)
    {
      v4f x0a = *(const v4f*)(Xt[0] + lane * 4);
      v4f x0b = *(const v4f*)(Xt[0] + 256 + lane * 4);
      v2f xs0[4] = {lo2(x0a), hi2(x0a), lo2(x0b), hi2(x0b)};
#pragma unroll
      for (int k = 0; k < 4; ++k) hr[k] = bdv[k] * xs0[k];
    }
#pragma unroll 1
    for (int i = 0; i < NBLK; ++i) {
      const float* RSs = RS[i % 3];
      const float* Xc  = Xt[i % 3];
      const float* Xn  = Xt[(i + 1) % 3];
#pragma unroll
      for (int u = 0; u < BLK; ++u) {
        const float* xrow = (u < 7) ? (Xc + (u + 1) * 512) : Xn;
        cstep(i * BLK + u, RSs, xrow, (u == 0) && (i == 0));
      }
      __syncthreads();
    }
  }
}

extern "C" void kernel_launch(void* const* d_in, const int* in_sizes, int n_in,
                              void* d_out, int out_size, void* d_ws, size_t ws_size,
                              hipStream_t stream) {
  const float* x    = (const float*)d_in[0];   // [8,4096,512]
  const float* vol  = (const float*)d_in[1];   // [8,4096,1]
  const float* llr  = (const float*)d_in[2];   // [512]
  const float* logb = (const float*)d_in[3];   // [512,1]
  const float* cvec = (const float*)d_in[4];   // [1,512]
  const float* logd = (const float*)d_in[5];   // [1]
  const float* lstp = (const float*)d_in[6];   // [512]
  const float* vgat = (const float*)d_in[7];   // [512]
  const float* alph = (const float*)d_in[8];   // [1]
  const float* lnw  = (const float*)d_in[9];   // [512]
  const float* lnb  = (const float*)d_in[10];  // [512]
  float* outf = (float*)d_out;

  ssm_scan<<<BATCH, 192, 0, stream>>>(x, vol, llr, logb, cvec, lstp,
                                      vgat, lnw, lnb, alph, logd, outf);
}

// Round 6
// 869.332 us; speedup vs baseline: 2.1463x; 2.1463x over previous
//
#include <hip/hip_runtime.h>
#include <cstdint>
#include <cstddef>

#define BATCH 8
#define SEQ   4096
#define DS    512
#define JPL   8              // states per lane (64 lanes * 8 = 512)
#define BLK   8              // time steps per LDS block
#define NBLK  (SEQ / BLK)    // 512
#define LN_EPS 1e-5f

typedef float v2f __attribute__((ext_vector_type(2)));
typedef float v4f __attribute__((ext_vector_type(4)));

static __device__ __forceinline__ v2f lo2(v4f x) { return __builtin_shufflevector(x, x, 0, 1); }
static __device__ __forceinline__ v2f hi2(v4f x) { return __builtin_shufflevector(x, x, 2, 3); }

#define LGKM0() asm volatile("s_waitcnt lgkmcnt(0)" ::: "memory")

// ---- DPP wave64 reduction: row_shr 1/2/4/8, row_bcast15/31 -> lane 63 ----
template <int CTRL>
__device__ __forceinline__ float dpp_add(float v) {
  int t = __builtin_amdgcn_update_dpp(0, __builtin_bit_cast(int, v), CTRL, 0xF, 0xF, true);
  return v + __builtin_bit_cast(float, t);
}
__device__ __forceinline__ float wave_sum64(float v) {
  v = dpp_add<0x111>(v);
  v = dpp_add<0x112>(v);
  v = dpp_add<0x114>(v);
  v = dpp_add<0x118>(v);
  v = dpp_add<0x142>(v);
  v = dpp_add<0x143>(v);
  return v;  // valid in lane 63
}
__device__ __forceinline__ float bcast63(float v) {
  return __builtin_bit_cast(float, __builtin_amdgcn_readlane(__builtin_bit_cast(int, v), 63));
}

// async HBM -> LDS: per-lane 16B from g, LDS dest = uniform base + lane*16
__device__ __forceinline__ void ld16(const float* g, float* l) {
  __builtin_amdgcn_global_load_lds(
      (const __attribute__((address_space(1))) void*)g,
      (__attribute__((address_space(3))) void*)l, 16, 0, 0);
}

// ---------------- scan kernel: 3 waves per batch element --------------------
// wave 0 (consumer): recurrence; LDS rows prefetched 2 steps ahead in regs.
// wave 1: DMA x 2 blocks ahead (counted vmcnt, never drains prefetch) + out.
// wave 2: rg = 1/(1+sigmoid(g)*v) + sum(c*bias*rg); vol 2 intervals ahead.
// One barrier per 8-step interval; consumer uses __syncthreads (no vmem),
// waves 1/2 use raw s_barrier with explicit counted waits.
__global__ __launch_bounds__(192, 1) void ssm_scan(
    const float* __restrict__ x, const float* __restrict__ vol,
    const float* __restrict__ llr, const float* __restrict__ logb,
    const float* __restrict__ cvec, const float* __restrict__ lstp,
    const float* __restrict__ vgat, const float* __restrict__ lnw,
    const float* __restrict__ lnb, const float* __restrict__ alph,
    const float* __restrict__ logd, float* __restrict__ out)
{
  __shared__ __attribute__((aligned(16))) float X[4][4096];          // 64KB, 4-deep
  __shared__ __attribute__((aligned(16))) float R0[4096], R1[4096];  // rg tiles
  __shared__ __attribute__((aligned(16))) float SC0[512], SC1[512];  // readout partials
  __shared__ __attribute__((aligned(16))) float SB0[512], SB1[512];  // sum(c*bias*rg)

  const int b    = blockIdx.x;
  const int lane = threadIdx.x & 63;
  const int wid  = threadIdx.x >> 6;

  if (wid == 1) {
    // ============ DMA-first + out-write wave (counted vmcnt) ============
    const float* xg = x + (size_t)b * SEQ * DS + lane * JPL;
    float* ob = out + (size_t)b * SEQ * DS;
    float al   = 1.0f / (1.0f + expf(-alph[0]));
    float dd   = expf(logd[0]);
    float coef = __builtin_fmaf(1.0f - al, dd, al);  // al + (1-al)*d
    float c1   = 1.0f - al;

    auto dma_blk = [&](int blk) {                 // 16 vmem loads
      float* Xs = X[blk & 3];
#pragma unroll
      for (int u = 0; u < BLK; ++u) {
        const float* row = xg + (size_t)(blk * BLK + u) * DS;
        ld16(row,     Xs + u * 512);
        ld16(row + 4, Xs + u * 512 + 256);
      }
    };
    auto out_blk = [&](int blk) {                 // 16 vmem stores
      const float* SCs = (blk & 1) ? SC1 : SC0;
      const float* Xs  = X[blk & 3];
#pragma unroll
      for (int u = 0; u < BLK; ++u) {
        float s  = bcast63(wave_sum64(SCs[u * 64 + lane]));
        float sc = c1 * s;
        v4f xa = *(const v4f*)(Xs + u * 512 + lane * 4);
        v4f xb = *(const v4f*)(Xs + u * 512 + 256 + lane * 4);
        float* row = ob + (size_t)(blk * BLK + u) * DS + lane * 8;
        *(v4f*)(row)     = xa * coef + sc;
        *(v4f*)(row + 4) = xb * coef + sc;
      }
    };

    // prologue: stage blocks 0,1; seal block 0 (block 1 stays in flight)
    dma_blk(0);
    dma_blk(1);
    asm volatile("s_waitcnt vmcnt(16)" ::: "memory");
    __builtin_amdgcn_s_barrier();
    // interval i: issue dma(i+2) FIRST, then out(i-1); seal dma(i+1).
    //   steady state in-flight at the wait: dma(i+2):16 + stores(i-1):16 = 32
#pragma unroll 1
    for (int i = 0; i < NBLK; ++i) {
      if (i + 2 < NBLK) dma_blk(i + 2);
      if (i >= 1) out_blk(i - 1);
      if (i == 0) {
        asm volatile("s_waitcnt vmcnt(16)" ::: "memory");  // seal dma(1)
      } else if (i + 2 < NBLK) {
        asm volatile("s_waitcnt vmcnt(32)" ::: "memory");  // seal dma(i+1)
      } else {
        asm volatile("s_waitcnt vmcnt(16)" ::: "memory");  // tail: stores only
      }
      __builtin_amdgcn_s_barrier();
    }
    out_blk(NBLK - 1);
  } else if (wid == 2) {
    // ============ gate-reciprocal + c*bias*rg wave ============
    v2f gate[4];
#pragma unroll
    for (int j = 0; j < JPL; ++j)
      gate[j >> 1][j & 1] = 1.0f / (1.0f + expf(-vgat[lane * JPL + j]));
    v4f cb0, cb1;  // c*bias per state
#pragma unroll
    for (int m = 0; m < 4; ++m) {
      int n0 = lane * JPL + m, n1 = lane * JPL + 4 + m;
      cb0[m] = cvec[n0] * lnb[n0];
      cb1[m] = cvec[n1] * lnb[n1];
    }
    const float* vg = vol + (size_t)b * SEQ;

    auto rg_blk = [&](v4f Va, v4f Vb, float* Rs, float* SBs) {
#pragma unroll
      for (int u = 0; u < BLK; ++u) {
        float vt = (u < 4) ? Va[u] : Vb[u - 4];
        v4f r0, r1;
#pragma unroll
        for (int k = 0; k < 4; ++k) {
          v2f den = gate[k] * vt + 1.0f;
          float q0 = __builtin_amdgcn_rcpf(den.x);
          float q1 = __builtin_amdgcn_rcpf(den.y);
          if (k < 2) { r0[2 * k] = q0; r0[2 * k + 1] = q1; }
          else       { r1[2 * (k - 2)] = q0; r1[2 * (k - 2) + 1] = q1; }
        }
        *(v4f*)(Rs + u * 512 + lane * 4)       = r0;
        *(v4f*)(Rs + u * 512 + 256 + lane * 4) = r1;
        v4f md = cb0 * r0;
        md = __builtin_elementwise_fma(cb1, r1, md);
        v2f mh = lo2(md) + hi2(md);
        SBs[u * 64 + lane] = mh.x + mh.y;
      }
    };

    // prologue: rg(0) direct; preload V1<-block1, V2<-block2
    v4f V1a = *(const v4f*)(vg + 1 * BLK), V1b = *(const v4f*)(vg + 1 * BLK + 4);
    v4f V2a = *(const v4f*)(vg + 2 * BLK), V2b = *(const v4f*)(vg + 2 * BLK + 4);
    {
      v4f V0a = *(const v4f*)(vg + 0), V0b = *(const v4f*)(vg + 4);
      rg_blk(V0a, V0b, R0, SB0);
    }
    LGKM0();
    __builtin_amdgcn_s_barrier();
    // interval i2: rg(i2+1) with V1; prefetch block i2+3 into V1 (used i2+2)
#pragma unroll 1
    for (int i2 = 0; i2 < NBLK; i2 += 2) {
      if (i2 + 1 < NBLK) rg_blk(V1a, V1b, (i2 & 1) ? R0 : R1,
                                (i2 & 1) ? SB0 : SB1);   // block i2+1 -> R[(i2+1)&1]
      if (i2 + 3 < NBLK) {
        V1a = *(const v4f*)(vg + (i2 + 3) * BLK);
        V1b = *(const v4f*)(vg + (i2 + 3) * BLK + 4);
      }
      LGKM0();
      __builtin_amdgcn_s_barrier();
      if (i2 + 2 < NBLK) rg_blk(V2a, V2b, R0, SB0);      // block i2+2 (even)
      if (i2 + 4 < NBLK) {
        V2a = *(const v4f*)(vg + (i2 + 4) * BLK);
        V2b = *(const v4f*)(vg + (i2 + 4) * BLK + 4);
      }
      LGKM0();
      __builtin_amdgcn_s_barrier();
    }
  } else {
    // ======================== consumer wave ========================
    v2f bd[4], aw[4], ab[4], cw[4];
#pragma unroll
    for (int j = 0; j < JPL; ++j) {
      int n = lane * JPL + j;
      float lam = -expf(llr[n]);
      float st  = expf(lstp[n]);
      float z   = st * lam;
      float ad  = (2.0f + z) / (2.0f - z);
      float bdv = st * (1.0f + ad) * expf(logb[n]) * 0.5f;
      float wv  = lnw[n], bi = lnb[n], cv = cvec[n];
      bd[j >> 1][j & 1] = bdv;
      aw[j >> 1][j & 1] = ad * wv;
      ab[j >> 1][j & 1] = ad * bi;
      cw[j >> 1][j & 1] = cv * wv;
    }
    v2f hp[4];
#pragma unroll
    for (int k = 0; k < 4; ++k) hp[k] = (v2f){0.0f, 0.0f};

    auto proc_blk = [&](const float* Xs, const float* Rs, const float* SBs, float* SCs) {
      // 2-step rolling register prefetch: LDS latency off the serial spine.
      v4f px0[2], px1[2], pr0[2], pr1[2];
      float psb[2];
#pragma unroll
      for (int u = 0; u < 2; ++u) {
        px0[u] = *(const v4f*)(Xs + u * 512 + lane * 4);
        px1[u] = *(const v4f*)(Xs + u * 512 + 256 + lane * 4);
        pr0[u] = *(const v4f*)(Rs + u * 512 + lane * 4);
        pr1[u] = *(const v4f*)(Rs + u * 512 + 256 + lane * 4);
        psb[u] = SBs[u * 64 + lane];
      }
#pragma unroll
      for (int u = 0; u < BLK; ++u) {
        const int sl = u & 1;                    // constant after unroll
        v4f xx0 = px0[sl], xx1 = px1[sl];
        v4f rr0 = pr0[sl], rr1 = pr1[sl];
        float u3s = psb[sl];
        if (u + 2 < BLK) {                       // refill the consumed slot
          px0[sl] = *(const v4f*)(Xs + (u + 2) * 512 + lane * 4);
          px1[sl] = *(const v4f*)(Xs + (u + 2) * 512 + 256 + lane * 4);
          pr0[sl] = *(const v4f*)(Rs + (u + 2) * 512 + lane * 4);
          pr1[sl] = *(const v4f*)(Rs + (u + 2) * 512 + 256 + lane * 4);
          psb[sl] = SBs[(u + 2) * 64 + lane];
        }
        v2f xs[4] = {lo2(xx0), hi2(xx0), lo2(xx1), hi2(xx1)};
        v2f rs[4] = {lo2(rr0), hi2(rr0), lo2(rr1), hi2(rr1)};

        v2f hr[4], q[4], abrs[4];
#pragma unroll
        for (int k = 0; k < 4; ++k) {
          hr[k]   = __builtin_elementwise_fma(bd[k], xs[k], hp[k]);  // hr = hp + bd*x
          q[k]    = rs[k] * hr[k];
          abrs[k] = ab[k] * rs[k];
        }
        v2f t01 = hr[0] + hr[1], t23 = hr[2] + hr[3];
        v2f tt  = t01 + t23;
        float s1 = tt.x + tt.y;
        v2f m01 = hr[0] * hr[0];
        m01 = __builtin_elementwise_fma(hr[1], hr[1], m01);
        v2f m23 = hr[2] * hr[2];
        m23 = __builtin_elementwise_fma(hr[3], hr[3], m23);
        v2f mm = m01 + m23;
        float s2 = mm.x + mm.y;

        s1 = bcast63(wave_sum64(s1));
        s2 = bcast63(wave_sum64(s2));
        float mu  = s1 * (1.0f / DS);
        float m2e = __builtin_fmaf(s2, 1.0f / DS, LN_EPS);
        float var = __builtin_fmaf(-mu, mu, m2e);
        float inv = __builtin_amdgcn_rsqf(var);

        v2f muv = {mu, mu}, invv = {inv, inv};
        v2f tv[4];
#pragma unroll
        for (int k = 0; k < 4; ++k)
          tv[k] = __builtin_elementwise_fma(-muv, rs[k], q[k]);  // rs*(hr-mu)
#pragma unroll
        for (int k = 0; k < 4; ++k) {
          v2f sv = aw[k] * tv[k];
          hp[k]  = __builtin_elementwise_fma(invv, sv, abrs[k]);
        }
        v2f u0 = cw[0] * tv[0];
        u0 = __builtin_elementwise_fma(cw[1], tv[1], u0);
        v2f u2 = cw[2] * tv[2];
        u2 = __builtin_elementwise_fma(cw[3], tv[3], u2);
        v2f uu = u0 + u2;
        float u1s = uu.x + uu.y;
        SCs[u * 64 + lane] = __builtin_fmaf(inv, u1s, u3s);
      }
    };

    __syncthreads();  // prologue barrier
#pragma unroll 1
    for (int i = 0; i < NBLK; ++i) {
      proc_blk(X[i & 3], (i & 1) ? R1 : R0,
               (i & 1) ? SB1 : SB0, (i & 1) ? SC1 : SC0);
      __syncthreads();  // consumer has no vmem: drain-free
    }
  }
}

extern "C" void kernel_launch(void* const* d_in, const int* in_sizes, int n_in,
                              void* d_out, int out_size, void* d_ws, size_t ws_size,
                              hipStream_t stream) {
  const float* x    = (const float*)d_in[0];   // [8,4096,512]
  const float* vol  = (const float*)d_in[1];   // [8,4096,1]
  const float* llr  = (const float*)d_in[2];   // [512]
  const float* logb = (const float*)d_in[3];   // [512,1]
  const float* cvec = (const float*)d_in[4];   // [1,512]
  const float* logd = (const float*)d_in[5];   // [1]
  const float* lstp = (const float*)d_in[6];   // [512]
  const float* vgat = (const float*)d_in[7];   // [512]
  const float* alph = (const float*)d_in[8];   // [1]
  const float* lnw  = (const float*)d_in[9];   // [512]
  const float* lnb  = (const float*)d_in[10];  // [512]
  float* outf = (float*)d_out;

  ssm_scan<<<BATCH, 192, 0, stream>>>(x, vol, llr, logb, cvec, lstp,
                                      vgat, lnw, lnb, alph, logd, outf);
}